// Round 14
// baseline (330.356 us; speedup 1.0000x reference)
//
#include <hip/hip_runtime.h>
#include <hip/hip_bf16.h>
#include <math.h>

// Problem constants
#define B_   32
#define S_   128
#define V_   30000
#define D_   300
#define P_   200
#define NT   8192         // 2*B*S token rows: x1 rows 0..4095, x2 rows 4096..8191
#define NT1  4096
// Aligned strides (64B rows)
#define LDE  320          // E-class buffers [NT,300] padded
#define LDP  256          // P-class buffers [NT,200] padded

typedef __hip_bfloat16 bf16;
typedef __attribute__((ext_vector_type(8))) __bf16 bf16x8;
typedef __attribute__((ext_vector_type(4))) float f32x4;

__device__ __forceinline__ float b2f(bf16 v) { return __bfloat162float(v); }
__device__ __forceinline__ short f2s(float v) { bf16 h = __float2bfloat16(v); return *(short*)&h; }
__device__ __forceinline__ float s2f(short s) { bf16 h; *(short*)&h = s; return __bfloat162float(h); }

// ---------------------------------------------------------------------------
// Mega setup kernel: (a) 8 standard weight conversions -> bf16 WT[Npad][Kpad]
// (IL=1: h/t column interleave), (b) combined cmp_W1 (decomposed concat),
// (c) embedding gather fp32 emb -> bf16 Eb [NT,LDE].
// ---------------------------------------------------------------------------
struct ConvTable {
    const float* W1[8]; const float* W2[8]; bf16* dst[8];
    int K[8], N1[8], N2[8], Kpad[8], IL[8];
    unsigned long long base[8]; unsigned long long total;   // convw range
};

__global__ void k_setup(ConvTable T, const float* __restrict__ Wc, bf16* __restrict__ dstc,
                        const int* __restrict__ x1, const int* __restrict__ x2,
                        const float* __restrict__ emb, bf16* __restrict__ E) {
    unsigned long long idx = (unsigned long long)blockIdx.x * 256 + threadIdx.x;
    if (idx < T.total) {
        int e = 0;
#pragma unroll
        for (int i = 1; i < 8; ++i) if (idx >= T.base[i]) e = i;
        unsigned long long local = idx - T.base[e];
        int Kpad = T.Kpad[e];
        int n = (int)(local / Kpad);
        int k = (int)(local - (unsigned long long)n * Kpad);
        float v = 0.f;
        if (k < T.K[e]) {
            if (T.IL[e]) {
                int d = n >> 1, half = n & 1;
                if (d < T.N1[e]) v = (half ? T.W2[e] : T.W1[e])[(size_t)k * T.N1[e] + d];
            } else {
                if (n < T.N1[e]) v = T.W1[e][(size_t)k * T.N1[e] + n];
                else if (n < T.N1[e] + T.N2[e]) v = T.W2[e][(size_t)k * T.N2[e] + (n - T.N1[e])];
            }
        }
        T.dst[e][local] = __float2bfloat16(v);
        return;
    }
    idx -= T.total;
    if (idx < 245760) {           // combined cmp_W1 -> dstc[256][960]
        int n = (int)idx / 960, k = (int)idx - n * 960;
        int sel = k / 320, kc = k - sel * 320;
        float v = 0.f;
        if (kc < 300 && n < 200) {
            if (sel == 0)      v = Wc[(size_t)kc * 200 + n] + Wc[(size_t)(600 + kc) * 200 + n];
            else if (sel == 1) v = Wc[(size_t)(300 + kc) * 200 + n] - Wc[(size_t)(600 + kc) * 200 + n];
            else               v = Wc[(size_t)(900 + kc) * 200 + n];
        }
        dstc[idx] = __float2bfloat16(v);
        return;
    }
    idx -= 245760;
    if (idx < (unsigned long long)NT * (LDE / 4)) {   // embed gather
        int r = (int)(idx / (LDE / 4));
        int c4 = ((int)idx - r * (LDE / 4)) * 4;
        int tok = (r < NT1) ? x1[r] : x2[r - NT1];
        if ((unsigned)tok >= (unsigned)V_) tok = 0;
        short o[4];
        if (c4 + 4 <= 300) {
            float4 v = *(const float4*)(emb + (size_t)tok * 300 + c4);
            o[0] = f2s(v.x); o[1] = f2s(v.y); o[2] = f2s(v.z); o[3] = f2s(v.w);
        } else {
#pragma unroll
            for (int i = 0; i < 4; ++i) {
                int c = c4 + i;
                o[i] = f2s((c < 300) ? emb[(size_t)tok * 300 + c] : 0.f);
            }
        }
        *(short4*)((short*)E + (size_t)r * LDE + c4) = *(short4*)&o[0];
    }
}

// ---------------------------------------------------------------------------
// Fused MFMA GEMM, BK=64. Tile 64(M) x 64(N), 4 waves 2x2, 32x32 each.
// (validated rounds 12-13). Grid: x = row-tile (XCD-local), y = col stripe.
// ---------------------------------------------------------------------------
template <int AMODE, int EPI>
__global__ __launch_bounds__(256) void k_gemm(
    const bf16* __restrict__ A, const bf16* __restrict__ A2,
    const bf16* __restrict__ A3, int lda,
    const bf16* __restrict__ WT, const bf16* __restrict__ WT2, int Kpad, int K,
    bf16* __restrict__ C, bf16* __restrict__ C2, int ldc, int Ntot, int N1,
    const float* __restrict__ bias1, const float* __restrict__ bias2,
    int act1, int act2, const bf16* __restrict__ xbuf, int ldxb)
{
    __shared__ short As[64][72];
    __shared__ short Bs[64][72];
    int tid = threadIdx.x;
    int w = tid >> 6, lane = tid & 63, quad = lane >> 4, l16 = lane & 15;
    int bm = blockIdx.x * 64;
    int half = 0, bn;
    if (AMODE == 4) { half = blockIdx.y >> 2; bn = (blockIdx.y & 3) * 64; }
    else bn = blockIdx.y * 64;
    const short* Wsh = (const short*)((AMODE == 4 && half) ? WT2 : WT);
    bf16* Cl = (AMODE == 4 && half) ? C2 : C;
    int wr = (w & 1) * 32, wc = (w >> 1) * 32;
    int ar = tid >> 2, ac = (tid & 3) * 16;

    const short* Abase = (const short*)A + (AMODE == 4 ? half * 200 : 0);
    int gm = bm + ar;

    f32x4 acc[2][2];
#pragma unroll
    for (int i = 0; i < 2; ++i)
#pragma unroll
        for (int j = 0; j < 2; ++j)
#pragma unroll
            for (int r = 0; r < 4; ++r) acc[i][j][r] = 0.f;

    short pa[16], pb[16];

    auto loadA = [&](int k0) {
        if (AMODE != 3) {
            int k = k0 + ac;
            const short* src = Abase + (size_t)gm * lda + k;
            if (k + 16 <= K) {
#pragma unroll
                for (int i = 0; i < 4; ++i) *(short4*)&pa[i * 4] = ((const short4*)src)[i];
            } else {
#pragma unroll
                for (int i = 0; i < 16; ++i) pa[i] = (k + i < K) ? src[i] : (short)0;
            }
        } else {
            int sel = k0 / 320;                 // wave-uniform (320 % 64 == 0)
            const short* base = (sel == 0) ? (const short*)A
                              : (sel == 1) ? (const short*)A2 : (const short*)A3;
            int k = (k0 - sel * 320) + ac;
            const short* src = base + (size_t)gm * LDE + k;
            if (k + 16 <= 300) {
#pragma unroll
                for (int i = 0; i < 4; ++i) *(short4*)&pa[i * 4] = ((const short4*)src)[i];
            } else {
#pragma unroll
                for (int i = 0; i < 16; ++i) pa[i] = (k + i < 300) ? src[i] : (short)0;
            }
        }
    };
    auto loadB = [&](int k0) {
        const short* src = Wsh + (size_t)(bn + ar) * Kpad + k0 + ac;
#pragma unroll
        for (int i = 0; i < 4; ++i) *(short4*)&pb[i * 4] = ((const short4*)src)[i];
    };

    loadA(0); loadB(0);
    for (int k0 = 0; k0 < Kpad; k0 += 64) {
#pragma unroll
        for (int i = 0; i < 4; ++i) {
            *(short4*)&As[ar][ac + i * 4] = *(short4*)&pa[i * 4];
            *(short4*)&Bs[ar][ac + i * 4] = *(short4*)&pb[i * 4];
        }
        __syncthreads();
        if (k0 + 64 < Kpad) { loadA(k0 + 64); loadB(k0 + 64); }
        {
            bf16x8 a[2][2], b[2][2];
#pragma unroll
            for (int mt = 0; mt < 2; ++mt)
#pragma unroll
                for (int ks = 0; ks < 2; ++ks)
                    a[mt][ks] = *(const bf16x8*)&As[wr + mt * 16 + l16][ks * 32 + quad * 8];
#pragma unroll
            for (int nt = 0; nt < 2; ++nt)
#pragma unroll
                for (int ks = 0; ks < 2; ++ks)
                    b[nt][ks] = *(const bf16x8*)&Bs[wc + nt * 16 + l16][ks * 32 + quad * 8];
#pragma unroll
            for (int mt = 0; mt < 2; ++mt)
#pragma unroll
                for (int nt = 0; nt < 2; ++nt) {
                    acc[mt][nt] = __builtin_amdgcn_mfma_f32_16x16x32_bf16(a[mt][0], b[nt][0], acc[mt][nt], 0, 0, 0);
                    acc[mt][nt] = __builtin_amdgcn_mfma_f32_16x16x32_bf16(a[mt][1], b[nt][1], acc[mt][nt], 0, 0, 0);
                }
        }
        __syncthreads();
    }
    short (*Cs)[72] = As;
#pragma unroll
    for (int mt = 0; mt < 2; ++mt) {
#pragma unroll
        for (int nt = 0; nt < 2; ++nt) {
            int cl = wc + nt * 16 + l16;
            int col = bn + cl;
            float bv; int act;
            if (EPI == 1) {
                int d = col >> 1;
                if (d > N1 - 1) d = N1 - 1;
                if (col & 1) { bv = bias2[d]; act = 2; }   // t: sigmoid
                else         { bv = bias1[d]; act = 1; }   // h: relu
            } else if (AMODE == 4) {
                int cc = (col < N1) ? col : (N1 - 1);
                bv = (half ? bias2 : bias1)[cc]; act = act1;
            } else {
                int cc = (col < Ntot) ? col : (Ntot - 1);
                if (cc < N1) { bv = bias1[cc]; act = act1; }
                else { bv = bias2[cc - N1]; act = act2; }
            }
#pragma unroll
            for (int r = 0; r < 4; ++r) {
                float v = acc[mt][nt][r] + bv;
                if (act == 1) v = fmaxf(v, 0.f);
                else if (act == 2) v = 1.f / (1.f + expf(-v));
                Cs[wr + mt * 16 + quad * 4 + r][cl] = f2s(v);
            }
        }
    }
    __syncthreads();
    if (EPI == 0) {
#pragma unroll
        for (int it = 0; it < 2; ++it) {
            int chunk = tid + it * 256;
            int rl = chunk >> 3;
            int c8 = (chunk & 7) * 8;
            short* dst = (short*)Cl + (size_t)(bm + rl) * ldc + bn + c8;
            *(short4*)dst = *(short4*)&Cs[rl][c8];
            *(short4*)(dst + 4) = *(short4*)&Cs[rl][c8 + 4];
        }
    } else {
        int d0 = bn >> 1;
#pragma unroll
        for (int it = 0; it < 2; ++it) {
            int chunk = tid + it * 256;
            int rl = chunk >> 3;
            int c4 = (chunk & 7) * 4;
            int row = bm + rl;
            const short* xs = (const short*)xbuf + (size_t)row * ldxb + d0 + c4;
            short o[4];
#pragma unroll
            for (int i = 0; i < 4; ++i) {
                float h = s2f(Cs[rl][2 * (c4 + i)]);
                float t = s2f(Cs[rl][2 * (c4 + i) + 1]);
                o[i] = f2s(t * h + (1.f - t) * s2f(xs[i]));
            }
            *(short4*)((short*)Cl + (size_t)row * ldc + d0 + c4) = *(short4*)&o[0];
        }
    }
}

// ---------------------------------------------------------------------------
// Transpose x2-halves of two [NT,*] (stride LDP) matrices into [B,P,S].
// ---------------------------------------------------------------------------
__global__ void k_transpose2(const bf16* __restrict__ srcP, bf16* __restrict__ dstP,
                             const bf16* __restrict__ srcQ, bf16* __restrict__ dstQ) {
    int idx = blockIdx.x * 256 + threadIdx.x;
    if (idx >= B_ * P_ * S_) return;
    const bf16* src = blockIdx.y ? srcQ : srcP;
    bf16* dst = blockIdx.y ? dstQ : dstP;
    int j = idx & (S_ - 1);
    int rest = idx >> 7;
    int p = rest % P_;
    int b = rest / P_;
    dst[idx] = src[((size_t)(b * S_ + j)) * LDP + p];
}

// ---------------------------------------------------------------------------
// sim kernel + fused BETA softmax. Block (b, it) owns SIM rows
// row0=b*128+it*8 .. +7 fully -> computes softmax_j in-LDS, writes Wb rows
// (beta half) directly; SIM still written for the alpha pass.
// ---------------------------------------------------------------------------
__global__ __launch_bounds__(256) void k_sim2(const bf16* __restrict__ Pmat,
                                              const bf16* __restrict__ Qmat,
                                              const bf16* __restrict__ PT,
                                              const bf16* __restrict__ QT,
                                              float* __restrict__ SIM,
                                              bf16* __restrict__ Wb) {
    __shared__ float qp[8][P_][2];
    __shared__ float sm[8][128];
    __shared__ float redm[8][32];
    int blk = blockIdx.x;
    int b = blk >> 4;
    int it = blk & 15;
    int tid = threadIdx.x;
    int j = tid & 127, h = tid >> 7;
    int row0 = b * 128 + it * 8;
    for (int x = tid; x < 8 * P_; x += 256) {
        int r = x / P_, c = x - r * P_;
        qp[r][c][0] = b2f(Qmat[(size_t)(row0 + r) * LDP + c]);
        qp[r][c][1] = b2f(Pmat[(size_t)(row0 + r) * LDP + c]);
    }
    __syncthreads();
    const bf16* ptb = PT + (size_t)b * P_ * S_;
    const bf16* qtb = QT + (size_t)b * P_ * S_;
    float acc[4] = {0.f, 0.f, 0.f, 0.f};
    for (int p = 0; p < P_; ++p) {
        float v = b2f(ptb[p * S_ + j]);
        float u = b2f(qtb[p * S_ + j]);
#pragma unroll
        for (int r = 0; r < 4; ++r) {
            int i = h * 4 + r;
            float2 w = *(const float2*)&qp[i][p][0];
            float d = w.x - u;
            acc[r] += w.y * v + __builtin_amdgcn_rcpf(1.f + fabsf(d));
        }
    }
#pragma unroll
    for (int r = 0; r < 4; ++r) {
        int lr = h * 4 + r;
        sm[lr][j] = acc[r];
        SIM[((size_t)(row0 + lr)) * S_ + j] = acc[r];
    }
    __syncthreads();
    // beta softmax for the 8 rows owned by this block
    int rr = tid >> 5, l32 = tid & 31;
    float v4[4];
    float m4 = -INFINITY;
#pragma unroll
    for (int i = 0; i < 4; ++i) { v4[i] = sm[rr][l32 * 4 + i]; m4 = fmaxf(m4, v4[i]); }
    redm[rr][l32] = m4;
    __syncthreads();
    for (int s = 16; s > 0; s >>= 1) {
        if (l32 < s) redm[rr][l32] = fmaxf(redm[rr][l32], redm[rr][l32 + s]);
        __syncthreads();
    }
    float mx = redm[rr][0];
    __syncthreads();
    float s4 = 0.f;
#pragma unroll
    for (int i = 0; i < 4; ++i) { v4[i] = expf(v4[i] - mx); s4 += v4[i]; }
    redm[rr][l32] = s4;
    __syncthreads();
    for (int s = 16; s > 0; s >>= 1) {
        if (l32 < s) redm[rr][l32] += redm[rr][l32 + s];
        __syncthreads();
    }
    float inv = 1.f / redm[rr][0];
    short o[4];
#pragma unroll
    for (int i = 0; i < 4; ++i) o[i] = f2s(v4[i] * inv);
    *(short4*)((short*)Wb + (size_t)(row0 + rr) * 128 + l32 * 4) = *(short4*)&o[0];
}

// ---------------------------------------------------------------------------
// Alpha softmax: Wb row 4096+blk = softmax_i SIM[b][i][r].
// ---------------------------------------------------------------------------
__global__ __launch_bounds__(128) void k_softa(const float* __restrict__ SIM,
                                               bf16* __restrict__ Wb) {
    int blk = blockIdx.x;
    int b = blk >> 7, r = blk & 127;
    int t = threadIdx.x;
    __shared__ float red[128];
    float x = SIM[((size_t)(b * S_ + t)) * S_ + r];
    red[t] = x;
    __syncthreads();
    for (int s = 64; s > 0; s >>= 1) {
        if (t < s) red[t] = fmaxf(red[t], red[t + s]);
        __syncthreads();
    }
    float mx = red[0];
    __syncthreads();
    float ex = expf(x - mx);
    red[t] = ex;
    __syncthreads();
    for (int s = 64; s > 0; s >>= 1) {
        if (t < s) red[t] += red[t + s];
        __syncthreads();
    }
    Wb[(size_t)(NT1 + blk) * 128 + t] = __float2bfloat16(ex / red[0]);
}

// ---------------------------------------------------------------------------
// Attention MFMA GEMM (validated round 13): ATT = Wb @ E-half; EA = ATT*E.
// ---------------------------------------------------------------------------
__global__ __launch_bounds__(256) void k_attg(const bf16* __restrict__ Wb,
                                              const bf16* __restrict__ E,
                                              bf16* __restrict__ ATT,
                                              bf16* __restrict__ EA) {
    __shared__ short As[64][72];
    __shared__ short Bs[64][72];
    int tid = threadIdx.x;
    int w = tid >> 6, lane = tid & 63, quad = lane >> 4, l16 = lane & 15;
    int m0 = blockIdx.x * 64;
    int kind = (m0 >= NT1) ? 1 : 0;
    int local = m0 - kind * NT1;
    int b = local >> 7;
    int ebase = kind ? (b * 128) : (NT1 + b * 128);   // opposite sentence rows
    int bn = blockIdx.y * 64;
    int wr = (w & 1) * 32, wc = (w >> 1) * 32;
    int ar = tid >> 2, ac = (tid & 3) * 16;

    f32x4 acc[2][2];
#pragma unroll
    for (int i = 0; i < 2; ++i)
#pragma unroll
        for (int j = 0; j < 2; ++j)
#pragma unroll
            for (int r = 0; r < 4; ++r) acc[i][j][r] = 0.f;

    for (int k0 = 0; k0 < 128; k0 += 64) {
        {
            const short* src = (const short*)Wb + (size_t)(m0 + ar) * 128 + k0 + ac;
#pragma unroll
            for (int i = 0; i < 4; ++i) *(short4*)&As[ar][ac + i * 4] = ((const short4*)src)[i];
        }
#pragma unroll
        for (int it = 0; it < 2; ++it) {
            int idx = tid + it * 256;
            int r = idx >> 3;
            int c8 = (idx & 7) * 8;
            const short* src = (const short*)E + (size_t)(ebase + k0 + r) * LDE + bn + c8;
            short4 v0 = ((const short4*)src)[0];
            short4 v1 = ((const short4*)src)[1];
            const short* vp = (const short*)&v0;
#pragma unroll
            for (int i = 0; i < 4; ++i) Bs[c8 + i][r] = vp[i];
            vp = (const short*)&v1;
#pragma unroll
            for (int i = 0; i < 4; ++i) Bs[c8 + 4 + i][r] = vp[i];
        }
        __syncthreads();
        {
            bf16x8 a[2][2], bb[2][2];
#pragma unroll
            for (int mt = 0; mt < 2; ++mt)
#pragma unroll
                for (int ks = 0; ks < 2; ++ks)
                    a[mt][ks] = *(const bf16x8*)&As[wr + mt * 16 + l16][ks * 32 + quad * 8];
#pragma unroll
            for (int nt = 0; nt < 2; ++nt)
#pragma unroll
                for (int ks = 0; ks < 2; ++ks)
                    bb[nt][ks] = *(const bf16x8*)&Bs[wc + nt * 16 + l16][ks * 32 + quad * 8];
#pragma unroll
            for (int mt = 0; mt < 2; ++mt)
#pragma unroll
                for (int nt = 0; nt < 2; ++nt) {
                    acc[mt][nt] = __builtin_amdgcn_mfma_f32_16x16x32_bf16(a[mt][0], bb[nt][0], acc[mt][nt], 0, 0, 0);
                    acc[mt][nt] = __builtin_amdgcn_mfma_f32_16x16x32_bf16(a[mt][1], bb[nt][1], acc[mt][nt], 0, 0, 0);
                }
        }
        __syncthreads();
    }
    short (*Cs)[72] = As;
#pragma unroll
    for (int mt = 0; mt < 2; ++mt)
#pragma unroll
        for (int nt = 0; nt < 2; ++nt) {
            int cl = wc + nt * 16 + l16;
#pragma unroll
            for (int r = 0; r < 4; ++r)
                Cs[wr + mt * 16 + quad * 4 + r][cl] = f2s(acc[mt][nt][r]);
        }
    __syncthreads();
#pragma unroll
    for (int it = 0; it < 2; ++it) {
        int chunk = tid + it * 256;
        int rl = chunk >> 3;
        int c8 = (chunk & 7) * 8;
        int row = m0 + rl;
        short a8[8];
        *(short4*)&a8[0] = *(short4*)&Cs[rl][c8];
        *(short4*)&a8[4] = *(short4*)&Cs[rl][c8 + 4];
        short* adst = (short*)ATT + (size_t)row * LDE + bn + c8;
        *(short4*)adst = *(short4*)&a8[0];
        *(short4*)(adst + 4) = *(short4*)&a8[4];
        const short* es = (const short*)E + (size_t)row * LDE + bn + c8;
        short e8[8];
        *(short4*)&e8[0] = ((const short4*)es)[0];
        *(short4*)&e8[4] = ((const short4*)es)[1];
        short o8[8];
#pragma unroll
        for (int i = 0; i < 8; ++i) o8[i] = f2s(s2f(a8[i]) * s2f(e8[i]));
        short* edst = (short*)EA + (size_t)row * LDE + bn + c8;
        *(short4*)edst = *(short4*)&o8[0];
        *(short4*)(edst + 4) = *(short4*)&o8[4];
    }
}

// ---------------------------------------------------------------------------
// Fused tail: pool -> agg1(relu) -> agg2(relu) -> out, one block per batch b.
// Uses ORIGINAL fp32 weights with coalesced [k*N+n] access; all intermediates
// in LDS. Writes final fp32 output.
// ---------------------------------------------------------------------------
__global__ __launch_bounds__(256) void k_tail(const bf16* __restrict__ V,
                                              const float* __restrict__ agg_W1,
                                              const float* __restrict__ agg_b1,
                                              const float* __restrict__ agg_W2,
                                              const float* __restrict__ agg_b2,
                                              const float* __restrict__ out_W,
                                              const float* __restrict__ out_b,
                                              float* __restrict__ out) {
    __shared__ float pool[800];
    __shared__ float g1[200];
    __shared__ float g2[200];
    int b = blockIdx.x;
    int t = threadIdx.x;
    if (t < 200) {
        const bf16* v1 = V + (size_t)(b * S_) * LDP;
        const bf16* v2 = V + (size_t)(NT1 + b * S_) * LDP;
        float mx1 = -INFINITY, mx2 = -INFINITY, s1 = 0.f, s2 = 0.f;
        for (int i = 0; i < S_; ++i) {
            float a = b2f(v1[(size_t)i * LDP + t]);
            mx1 = fmaxf(mx1, a); s1 += a;
            float bb = b2f(v2[(size_t)i * LDP + t]);
            mx2 = fmaxf(mx2, bb); s2 += bb;
        }
        pool[t] = mx1; pool[200 + t] = mx2; pool[400 + t] = s1; pool[600 + t] = s2;
    }
    __syncthreads();
    if (t < 200) {
        float acc = 0.f;
        for (int k = 0; k < 800; ++k) acc += pool[k] * agg_W1[(size_t)k * 200 + t];
        g1[t] = fmaxf(acc + agg_b1[t], 0.f);
    }
    __syncthreads();
    if (t < 200) {
        float acc = 0.f;
        for (int k = 0; k < 200; ++k) acc += g1[k] * agg_W2[(size_t)k * 200 + t];
        g2[t] = fmaxf(acc + agg_b2[t], 0.f);
    }
    __syncthreads();
    if (t < 3) {
        float acc = 0.f;
        for (int k = 0; k < 200; ++k) acc += g2[k] * out_W[(size_t)k * 3 + t];
        out[b * 3 + t] = acc + out_b[t];
    }
}

// Sentinel fill (diagnostic: absmax ~555 => ws_size too small)
__global__ void k_fillf(float* dst, int n, float v) {
    int i = blockIdx.x * 256 + threadIdx.x;
    if (i < n) dst[i] = v;
}

// ---------------------------------------------------------------------------
// Launch
// ---------------------------------------------------------------------------
extern "C" void kernel_launch(void* const* d_in, const int* in_sizes, int n_in,
                              void* d_out, int out_size, void* d_ws, size_t ws_size,
                              hipStream_t stream) {
    const int* x1 = (const int*)d_in[0];
    const int* x2 = (const int*)d_in[1];
    const float* emb = (const float*)d_in[2];
    const float *hw1_Wh = (const float*)d_in[3],  *hw1_bh = (const float*)d_in[4];
    const float *hw1_Wt = (const float*)d_in[5],  *hw1_bt = (const float*)d_in[6];
    const float *hw2_Wh = (const float*)d_in[7],  *hw2_bh = (const float*)d_in[8];
    const float *hw2_Wt = (const float*)d_in[9],  *hw2_bt = (const float*)d_in[10];
    const float *mul_W1 = (const float*)d_in[11], *mul_b1 = (const float*)d_in[12];
    const float *mul_W2 = (const float*)d_in[13], *mul_b2 = (const float*)d_in[14];
    const float *dist_W1 = (const float*)d_in[15], *dist_b1 = (const float*)d_in[16];
    const float *dist_W2 = (const float*)d_in[17], *dist_b2 = (const float*)d_in[18];
    const float *cmp_W1 = (const float*)d_in[19], *cmp_b1 = (const float*)d_in[20];
    const float *cmp_W2 = (const float*)d_in[21], *cmp_b2 = (const float*)d_in[22];
    const float *chw1_Wh = (const float*)d_in[23], *chw1_bh = (const float*)d_in[24];
    const float *chw1_Wt = (const float*)d_in[25], *chw1_bt = (const float*)d_in[26];
    const float *chw2_Wh = (const float*)d_in[27], *chw2_bh = (const float*)d_in[28];
    const float *chw2_Wt = (const float*)d_in[29], *chw2_bt = (const float*)d_in[30];
    const float *agg_W1 = (const float*)d_in[31], *agg_b1 = (const float*)d_in[32];
    const float *agg_W2 = (const float*)d_in[33], *agg_b2 = (const float*)d_in[34];
    const float *out_W = (const float*)d_in[35], *out_b = (const float*)d_in[36];

    // ---- Workspace layout (bf16 elems), all strides 64B-aligned ----
    const size_t nE = (size_t)NT * LDE;        // 2,621,440
    const size_t nP = (size_t)NT * LDP;        // 2,097,152
    const size_t nCht = (size_t)NT * 448;      // 3,670,016
    const size_t nTR = (size_t)B_ * P_ * S_;   //   819,200
    const size_t nWT = 1224704;                // converted bf16 weights
    size_t bf16_elems = 4 * nE + 2 * nP + 2 * nCht + nWT;
    size_t need = bf16_elems * 2 + 4096;
    if (ws_size < need) {
        k_fillf<<<dim3(1), dim3(256), 0, stream>>>((float*)d_out, B_ * 3, 555.f);
        return;
    }
    bf16* Eb  = (bf16*)d_ws;            // [NT,LDE] embed; later ATT (dead after hw1)
    bf16* X1  = Eb + nE;                // [NT,LDE]
    bf16* X2  = X1 + nE;                // [NT,LDE] final E
    bf16* EA  = X2 + nE;                // [NT,LDE] E*ATT
    bf16* Pb  = EA + nE;                // [NT,LDP]
    bf16* Qb  = Pb + nP;                // [NT,LDP]
    bf16* ChtA = Qb + nP;               // [NT,448]
    bf16* ChtB = ChtA + nCht;           // [NT,448] PT/QT/SIM overlay / V2
    bf16* WTp = ChtB + nCht;
    bf16* ATT = Eb;                     // overlay: Eb dead after hw1
    bf16* Wbuf = ChtA;                  // [8192][128] softmax weights overlay
    // overlays inside ChtB:
    bf16* PTb = ChtB;
    bf16* QTb = ChtB + nTR;
    float* SIM = (float*)(ChtB + 2 * nTR);
    bf16* V2 = ChtB;                    // reuse after attention

    // converted-weight sub-buffers, Kpad mult of 64
    bf16* WT_hw1 = WTp + 0;        // 640x320 interleaved h|t
    bf16* WT_hw2 = WTp + 204800;   // 640x320 interleaved
    bf16* WT_md  = WTp + 409600;   // 448x320 (mul_W1 | dist_W1)
    bf16* WT_m2  = WTp + 552960;   // 256x256
    bf16* WT_d2  = WTp + 618496;   // 256x256
    bf16* WT_c2  = WTp + 684032;   // 256x256
    bf16* WT_ch1 = WTp + 749568;   // 448x256 interleaved
    bf16* WT_ch2 = WTp + 864256;   // 448x256 interleaved
    bf16* WT_c1  = WTp + 978944;   // 256x960 (combined cmp_W1)

    dim3 blk256(256);

    // 0. mega setup: weight conversions + cmp_W1 combine + embed gather
    ConvTable T;
    const float* s1[8] = {hw1_Wh, hw2_Wh, mul_W1, mul_W2, dist_W2, cmp_W2, chw1_Wh, chw2_Wh};
    const float* s2[8] = {hw1_Wt, hw2_Wt, dist_W1, nullptr, nullptr, nullptr, chw1_Wt, chw2_Wt};
    bf16* dsts[8] = {WT_hw1, WT_hw2, WT_md, WT_m2, WT_d2, WT_c2, WT_ch1, WT_ch2};
    int Ks[8]  = {300, 300, 300, 200, 200, 200, 200, 200};
    int N1s[8] = {300, 300, 200, 200, 200, 200, 200, 200};
    int N2s[8] = {300, 300, 200, 0, 0, 0, 200, 200};
    int Kps[8] = {320, 320, 320, 256, 256, 256, 256, 256};
    int Nps[8] = {640, 640, 448, 256, 256, 256, 448, 448};
    int ILs[8] = {1, 1, 0, 0, 0, 0, 1, 1};
    unsigned long long base = 0;
    for (int i = 0; i < 8; ++i) {
        T.W1[i] = s1[i]; T.W2[i] = s2[i]; T.dst[i] = dsts[i];
        T.K[i] = Ks[i]; T.N1[i] = N1s[i]; T.N2[i] = N2s[i]; T.Kpad[i] = Kps[i];
        T.IL[i] = ILs[i];
        T.base[i] = base;
        base += (unsigned long long)Kps[i] * Nps[i];
    }
    T.total = base;   // 978,944
    unsigned long long setup_total = base + 245760ull + (unsigned long long)NT * (LDE / 4);
    k_setup<<<dim3((unsigned)((setup_total + 255) / 256)), blk256, 0, stream>>>(
        T, cmp_W1, WT_c1, x1, x2, emb, Eb);

    // 1. hw1: A=Eb, interleaved h|t, fused highway (x=Eb) -> X1
    k_gemm<0, 1><<<dim3(128, 10), blk256, 0, stream>>>(
        Eb, nullptr, nullptr, LDE,
        WT_hw1, nullptr, 320, 300, X1, nullptr, LDE, 600, 300,
        hw1_bh, hw1_bt, 1, 2, Eb, LDE);

    // 2. hw2: A=X1, fused highway (x=X1) -> X2
    k_gemm<0, 1><<<dim3(128, 10), blk256, 0, stream>>>(
        X1, nullptr, nullptr, LDE,
        WT_hw2, nullptr, 320, 300, X2, nullptr, LDE, 600, 300,
        hw2_bh, hw2_bt, 1, 2, X1, LDE);

    // 3. md: A=X2 -> ChtA [NT,448] (mul hidden | dist hidden)
    k_gemm<0, 0><<<dim3(128, 7), blk256, 0, stream>>>(
        X2, nullptr, nullptr, LDE,
        WT_md, nullptr, 320, 300, ChtA, nullptr, 448, 400, 200,
        mul_b1, dist_b1, 1, 1, nullptr, 0);

    // 4. m2 + d2 dual: ChtA halves -> Pb, Qb
    k_gemm<4, 0><<<dim3(128, 8), blk256, 0, stream>>>(
        ChtA, nullptr, nullptr, 448,
        WT_m2, WT_d2, 256, 200, Pb, Qb, LDP, 256, 200,
        mul_b2, dist_b2, 1, 1, nullptr, 0);

    // 5. transpose x2-halves into ChtB overlay
    int nTRb = (int)((nTR + 255) / 256);
    k_transpose2<<<dim3(nTRb, 2), blk256, 0, stream>>>(
        Pb + (size_t)NT1 * LDP, PTb, Qb + (size_t)NT1 * LDP, QTb);

    // 6. sim + fused beta softmax -> SIM + Wbuf[0:4096]
    k_sim2<<<dim3(B_ * 16), blk256, 0, stream>>>(Pb, Qb, PTb, QTb, SIM, Wbuf);

    // 7. alpha softmax -> Wbuf[4096:8192]
    k_softa<<<dim3(NT1), dim3(128), 0, stream>>>(SIM, Wbuf);

    // 8. attention MFMA: ATT = Wbuf @ E-half, EA = ATT*E fused; E = X2
    k_attg<<<dim3(128, 5), blk256, 0, stream>>>(Wbuf, X2, ATT, EA);

    // 9. cmp1: virtual K-concat {X2, ATT, EA} -> ChtA hidden [NT,LDP]
    k_gemm<3, 0><<<dim3(128, 4), blk256, 0, stream>>>(
        X2, ATT, EA, LDE,
        WT_c1, nullptr, 960, 300, ChtA, nullptr, LDP, 200, 200,
        cmp_b1, cmp_b1, 1, 1, nullptr, 0);

    // 10. cmp2: ChtA -> Pb (Vv0)
    k_gemm<0, 0><<<dim3(128, 4), blk256, 0, stream>>>(
        ChtA, nullptr, nullptr, LDP,
        WT_c2, nullptr, 256, 200, Pb, nullptr, LDP, 200, 200,
        cmp_b2, cmp_b2, 1, 1, nullptr, 0);

    // 11. ch1: A=Pb, interleaved h|t, fused highway (x=Pb) -> Qb (V1)
    k_gemm<0, 1><<<dim3(128, 7), blk256, 0, stream>>>(
        Pb, nullptr, nullptr, LDP,
        WT_ch1, nullptr, 256, 200, Qb, nullptr, LDP, 400, 200,
        chw1_bh, chw1_bt, 1, 2, Pb, LDP);

    // 12. ch2: A=Qb, fused highway (x=Qb) -> V2 (ChtB reuse)
    k_gemm<0, 1><<<dim3(128, 7), blk256, 0, stream>>>(
        Qb, nullptr, nullptr, LDP,
        WT_ch2, nullptr, 256, 200, V2, nullptr, LDP, 400, 200,
        chw2_bh, chw2_bt, 1, 2, Qb, LDP);

    // 13. fused tail: pool -> agg ff -> final linear -> d_out
    k_tail<<<dim3(B_), blk256, 0, stream>>>(V2, agg_W1, agg_b1, agg_W2, agg_b2,
                                            out_W, out_b, (float*)d_out);
}

// Round 15
// 313.596 us; speedup vs baseline: 1.0534x; 1.0534x over previous
//
#include <hip/hip_runtime.h>
#include <hip/hip_bf16.h>
#include <math.h>

// Problem constants
#define B_   32
#define S_   128
#define V_   30000
#define D_   300
#define P_   200
#define NT   8192         // 2*B*S token rows: x1 rows 0..4095, x2 rows 4096..8191
#define NT1  4096
// Aligned strides (64B rows)
#define LDE  320          // E-class buffers [NT,300] padded
#define LDP  256          // P-class buffers [NT,200] padded

typedef __hip_bfloat16 bf16;
typedef __attribute__((ext_vector_type(8))) __bf16 bf16x8;
typedef __attribute__((ext_vector_type(4))) float f32x4;

__device__ __forceinline__ float b2f(bf16 v) { return __bfloat162float(v); }
__device__ __forceinline__ short f2s(float v) { bf16 h = __float2bfloat16(v); return *(short*)&h; }
__device__ __forceinline__ float s2f(short s) { bf16 h; *(short*)&h = s; return __bfloat162float(h); }

// ---------------------------------------------------------------------------
// Mega setup kernel: (a) 8 standard weight conversions -> bf16 WT[Npad][Kpad]
// (IL=1: h/t column interleave), (b) combined cmp_W1 (decomposed concat),
// (c) embedding gather fp32 emb -> bf16 Eb [NT,LDE], (d) fp32 tail-weight
// transposes (agg_W1 -> [200][800], agg_W2 -> [200][200], out_W -> [3][200]).
// ---------------------------------------------------------------------------
struct ConvTable {
    const float* W1[8]; const float* W2[8]; bf16* dst[8];
    int K[8], N1[8], N2[8], Kpad[8], IL[8];
    unsigned long long base[8]; unsigned long long total;   // convw range
};

__global__ void k_setup(ConvTable T, const float* __restrict__ Wc, bf16* __restrict__ dstc,
                        const int* __restrict__ x1, const int* __restrict__ x2,
                        const float* __restrict__ emb, bf16* __restrict__ E,
                        const float* __restrict__ A1w, const float* __restrict__ A2w,
                        const float* __restrict__ Ow,
                        float* __restrict__ T1, float* __restrict__ T2,
                        float* __restrict__ T3) {
    unsigned long long idx = (unsigned long long)blockIdx.x * 256 + threadIdx.x;
    if (idx < T.total) {
        int e = 0;
#pragma unroll
        for (int i = 1; i < 8; ++i) if (idx >= T.base[i]) e = i;
        unsigned long long local = idx - T.base[e];
        int Kpad = T.Kpad[e];
        int n = (int)(local / Kpad);
        int k = (int)(local - (unsigned long long)n * Kpad);
        float v = 0.f;
        if (k < T.K[e]) {
            if (T.IL[e]) {
                int d = n >> 1, half = n & 1;
                if (d < T.N1[e]) v = (half ? T.W2[e] : T.W1[e])[(size_t)k * T.N1[e] + d];
            } else {
                if (n < T.N1[e]) v = T.W1[e][(size_t)k * T.N1[e] + n];
                else if (n < T.N1[e] + T.N2[e]) v = T.W2[e][(size_t)k * T.N2[e] + (n - T.N1[e])];
            }
        }
        T.dst[e][local] = __float2bfloat16(v);
        return;
    }
    idx -= T.total;
    if (idx < 245760) {           // combined cmp_W1 -> dstc[256][960]
        int n = (int)idx / 960, k = (int)idx - n * 960;
        int sel = k / 320, kc = k - sel * 320;
        float v = 0.f;
        if (kc < 300 && n < 200) {
            if (sel == 0)      v = Wc[(size_t)kc * 200 + n] + Wc[(size_t)(600 + kc) * 200 + n];
            else if (sel == 1) v = Wc[(size_t)(300 + kc) * 200 + n] - Wc[(size_t)(600 + kc) * 200 + n];
            else               v = Wc[(size_t)(900 + kc) * 200 + n];
        }
        dstc[idx] = __float2bfloat16(v);
        return;
    }
    idx -= 245760;
    if (idx < (unsigned long long)NT * (LDE / 4)) {   // embed gather
        int r = (int)(idx / (LDE / 4));
        int c4 = ((int)idx - r * (LDE / 4)) * 4;
        int tok = (r < NT1) ? x1[r] : x2[r - NT1];
        if ((unsigned)tok >= (unsigned)V_) tok = 0;
        short o[4];
        if (c4 + 4 <= 300) {
            float4 v = *(const float4*)(emb + (size_t)tok * 300 + c4);
            o[0] = f2s(v.x); o[1] = f2s(v.y); o[2] = f2s(v.z); o[3] = f2s(v.w);
        } else {
#pragma unroll
            for (int i = 0; i < 4; ++i) {
                int c = c4 + i;
                o[i] = f2s((c < 300) ? emb[(size_t)tok * 300 + c] : 0.f);
            }
        }
        *(short4*)((short*)E + (size_t)r * LDE + c4) = *(short4*)&o[0];
        return;
    }
    idx -= (unsigned long long)NT * (LDE / 4);
    int l = (int)idx;
    if (l < 160000)       T1[l] = A1w[(size_t)(l % 800) * 200 + l / 800];
    else if (l < 200000)  { int m = l - 160000; T2[m] = A2w[(size_t)(m % 200) * 200 + m / 200]; }
    else if (l < 200600)  { int m = l - 200000; T3[m] = Ow[(size_t)(m % 200) * 3 + m / 200]; }
}

// ---------------------------------------------------------------------------
// Skinny GEMM for tiny M (validated rounds 6-13): one wave per output elem.
// ---------------------------------------------------------------------------
__global__ __launch_bounds__(256) void k_skinny(
    const float* __restrict__ A, const float* __restrict__ WT,
    const float* __restrict__ bias, float* __restrict__ C,
    int M, int N, int K, int act) {
    int wave = (blockIdx.x * 256 + threadIdx.x) >> 6;
    int lane = threadIdx.x & 63;
    if (wave >= M * N) return;
    int m = wave / N, n = wave - m * N;
    const float4* a4 = (const float4*)(A + (size_t)m * K);
    const float4* w4 = (const float4*)(WT + (size_t)n * K);
    int K4 = K >> 2;
    float acc = 0.f;
    for (int i = lane; i < K4; i += 64) {
        float4 av = a4[i], wv = w4[i];
        acc += av.x * wv.x + av.y * wv.y + av.z * wv.z + av.w * wv.w;
    }
#pragma unroll
    for (int off = 32; off > 0; off >>= 1) acc += __shfl_down(acc, off, 64);
    if (lane == 0) {
        float v = acc + bias[n];
        if (act == 1) v = fmaxf(v, 0.f);
        C[(size_t)m * N + n] = v;
    }
}

// ---------------------------------------------------------------------------
// Fused MFMA GEMM, BK=64. Tile 64(M) x 64(N), 4 waves 2x2, 32x32 each.
// (validated rounds 12-13). Grid: x = row-tile (XCD-local), y = col stripe.
// ---------------------------------------------------------------------------
template <int AMODE, int EPI>
__global__ __launch_bounds__(256) void k_gemm(
    const bf16* __restrict__ A, const bf16* __restrict__ A2,
    const bf16* __restrict__ A3, int lda,
    const bf16* __restrict__ WT, const bf16* __restrict__ WT2, int Kpad, int K,
    bf16* __restrict__ C, bf16* __restrict__ C2, int ldc, int Ntot, int N1,
    const float* __restrict__ bias1, const float* __restrict__ bias2,
    int act1, int act2, const bf16* __restrict__ xbuf, int ldxb)
{
    __shared__ short As[64][72];
    __shared__ short Bs[64][72];
    int tid = threadIdx.x;
    int w = tid >> 6, lane = tid & 63, quad = lane >> 4, l16 = lane & 15;
    int bm = blockIdx.x * 64;
    int half = 0, bn;
    if (AMODE == 4) { half = blockIdx.y >> 2; bn = (blockIdx.y & 3) * 64; }
    else bn = blockIdx.y * 64;
    const short* Wsh = (const short*)((AMODE == 4 && half) ? WT2 : WT);
    bf16* Cl = (AMODE == 4 && half) ? C2 : C;
    int wr = (w & 1) * 32, wc = (w >> 1) * 32;
    int ar = tid >> 2, ac = (tid & 3) * 16;

    const short* Abase = (const short*)A + (AMODE == 4 ? half * 200 : 0);
    int gm = bm + ar;

    f32x4 acc[2][2];
#pragma unroll
    for (int i = 0; i < 2; ++i)
#pragma unroll
        for (int j = 0; j < 2; ++j)
#pragma unroll
            for (int r = 0; r < 4; ++r) acc[i][j][r] = 0.f;

    short pa[16], pb[16];

    auto loadA = [&](int k0) {
        if (AMODE != 3) {
            int k = k0 + ac;
            const short* src = Abase + (size_t)gm * lda + k;
            if (k + 16 <= K) {
#pragma unroll
                for (int i = 0; i < 4; ++i) *(short4*)&pa[i * 4] = ((const short4*)src)[i];
            } else {
#pragma unroll
                for (int i = 0; i < 16; ++i) pa[i] = (k + i < K) ? src[i] : (short)0;
            }
        } else {
            int sel = k0 / 320;                 // wave-uniform (320 % 64 == 0)
            const short* base = (sel == 0) ? (const short*)A
                              : (sel == 1) ? (const short*)A2 : (const short*)A3;
            int k = (k0 - sel * 320) + ac;
            const short* src = base + (size_t)gm * LDE + k;
            if (k + 16 <= 300) {
#pragma unroll
                for (int i = 0; i < 4; ++i) *(short4*)&pa[i * 4] = ((const short4*)src)[i];
            } else {
#pragma unroll
                for (int i = 0; i < 16; ++i) pa[i] = (k + i < 300) ? src[i] : (short)0;
            }
        }
    };
    auto loadB = [&](int k0) {
        const short* src = Wsh + (size_t)(bn + ar) * Kpad + k0 + ac;
#pragma unroll
        for (int i = 0; i < 4; ++i) *(short4*)&pb[i * 4] = ((const short4*)src)[i];
    };

    loadA(0); loadB(0);
    for (int k0 = 0; k0 < Kpad; k0 += 64) {
#pragma unroll
        for (int i = 0; i < 4; ++i) {
            *(short4*)&As[ar][ac + i * 4] = *(short4*)&pa[i * 4];
            *(short4*)&Bs[ar][ac + i * 4] = *(short4*)&pb[i * 4];
        }
        __syncthreads();
        if (k0 + 64 < Kpad) { loadA(k0 + 64); loadB(k0 + 64); }
        {
            bf16x8 a[2][2], b[2][2];
#pragma unroll
            for (int mt = 0; mt < 2; ++mt)
#pragma unroll
                for (int ks = 0; ks < 2; ++ks)
                    a[mt][ks] = *(const bf16x8*)&As[wr + mt * 16 + l16][ks * 32 + quad * 8];
#pragma unroll
            for (int nt = 0; nt < 2; ++nt)
#pragma unroll
                for (int ks = 0; ks < 2; ++ks)
                    b[nt][ks] = *(const bf16x8*)&Bs[wc + nt * 16 + l16][ks * 32 + quad * 8];
#pragma unroll
            for (int mt = 0; mt < 2; ++mt)
#pragma unroll
                for (int nt = 0; nt < 2; ++nt) {
                    acc[mt][nt] = __builtin_amdgcn_mfma_f32_16x16x32_bf16(a[mt][0], b[nt][0], acc[mt][nt], 0, 0, 0);
                    acc[mt][nt] = __builtin_amdgcn_mfma_f32_16x16x32_bf16(a[mt][1], b[nt][1], acc[mt][nt], 0, 0, 0);
                }
        }
        __syncthreads();
    }
    short (*Cs)[72] = As;
#pragma unroll
    for (int mt = 0; mt < 2; ++mt) {
#pragma unroll
        for (int nt = 0; nt < 2; ++nt) {
            int cl = wc + nt * 16 + l16;
            int col = bn + cl;
            float bv; int act;
            if (EPI == 1) {
                int d = col >> 1;
                if (d > N1 - 1) d = N1 - 1;
                if (col & 1) { bv = bias2[d]; act = 2; }   // t: sigmoid
                else         { bv = bias1[d]; act = 1; }   // h: relu
            } else if (AMODE == 4) {
                int cc = (col < N1) ? col : (N1 - 1);
                bv = (half ? bias2 : bias1)[cc]; act = act1;
            } else {
                int cc = (col < Ntot) ? col : (Ntot - 1);
                if (cc < N1) { bv = bias1[cc]; act = act1; }
                else { bv = bias2[cc - N1]; act = act2; }
            }
#pragma unroll
            for (int r = 0; r < 4; ++r) {
                float v = acc[mt][nt][r] + bv;
                if (act == 1) v = fmaxf(v, 0.f);
                else if (act == 2) v = 1.f / (1.f + expf(-v));
                Cs[wr + mt * 16 + quad * 4 + r][cl] = f2s(v);
            }
        }
    }
    __syncthreads();
    if (EPI == 0) {
#pragma unroll
        for (int it = 0; it < 2; ++it) {
            int chunk = tid + it * 256;
            int rl = chunk >> 3;
            int c8 = (chunk & 7) * 8;
            short* dst = (short*)Cl + (size_t)(bm + rl) * ldc + bn + c8;
            *(short4*)dst = *(short4*)&Cs[rl][c8];
            *(short4*)(dst + 4) = *(short4*)&Cs[rl][c8 + 4];
        }
    } else {
        int d0 = bn >> 1;
#pragma unroll
        for (int it = 0; it < 2; ++it) {
            int chunk = tid + it * 256;
            int rl = chunk >> 3;
            int c4 = (chunk & 7) * 4;
            int row = bm + rl;
            const short* xs = (const short*)xbuf + (size_t)row * ldxb + d0 + c4;
            short o[4];
#pragma unroll
            for (int i = 0; i < 4; ++i) {
                float h = s2f(Cs[rl][2 * (c4 + i)]);
                float t = s2f(Cs[rl][2 * (c4 + i) + 1]);
                o[i] = f2s(t * h + (1.f - t) * s2f(xs[i]));
            }
            *(short4*)((short*)Cl + (size_t)row * ldc + d0 + c4) = *(short4*)&o[0];
        }
    }
}

// ---------------------------------------------------------------------------
// Transpose x2-halves of two [NT,*] (stride LDP) matrices into [B,P,S].
// ---------------------------------------------------------------------------
__global__ void k_transpose2(const bf16* __restrict__ srcP, bf16* __restrict__ dstP,
                             const bf16* __restrict__ srcQ, bf16* __restrict__ dstQ) {
    int idx = blockIdx.x * 256 + threadIdx.x;
    if (idx >= B_ * P_ * S_) return;
    const bf16* src = blockIdx.y ? srcQ : srcP;
    bf16* dst = blockIdx.y ? dstQ : dstP;
    int j = idx & (S_ - 1);
    int rest = idx >> 7;
    int p = rest % P_;
    int b = rest / P_;
    dst[idx] = src[((size_t)(b * S_ + j)) * LDP + p];
}

// ---------------------------------------------------------------------------
// sim kernel + fused BETA softmax (validated round 14).
// ---------------------------------------------------------------------------
__global__ __launch_bounds__(256) void k_sim2(const bf16* __restrict__ Pmat,
                                              const bf16* __restrict__ Qmat,
                                              const bf16* __restrict__ PT,
                                              const bf16* __restrict__ QT,
                                              float* __restrict__ SIM,
                                              bf16* __restrict__ Wb) {
    __shared__ float qp[8][P_][2];
    __shared__ float sm[8][128];
    __shared__ float redm[8][32];
    int blk = blockIdx.x;
    int b = blk >> 4;
    int it = blk & 15;
    int tid = threadIdx.x;
    int j = tid & 127, h = tid >> 7;
    int row0 = b * 128 + it * 8;
    for (int x = tid; x < 8 * P_; x += 256) {
        int r = x / P_, c = x - r * P_;
        qp[r][c][0] = b2f(Qmat[(size_t)(row0 + r) * LDP + c]);
        qp[r][c][1] = b2f(Pmat[(size_t)(row0 + r) * LDP + c]);
    }
    __syncthreads();
    const bf16* ptb = PT + (size_t)b * P_ * S_;
    const bf16* qtb = QT + (size_t)b * P_ * S_;
    float acc[4] = {0.f, 0.f, 0.f, 0.f};
    for (int p = 0; p < P_; ++p) {
        float v = b2f(ptb[p * S_ + j]);
        float u = b2f(qtb[p * S_ + j]);
#pragma unroll
        for (int r = 0; r < 4; ++r) {
            int i = h * 4 + r;
            float2 w = *(const float2*)&qp[i][p][0];
            float d = w.x - u;
            acc[r] += w.y * v + __builtin_amdgcn_rcpf(1.f + fabsf(d));
        }
    }
#pragma unroll
    for (int r = 0; r < 4; ++r) {
        int lr = h * 4 + r;
        sm[lr][j] = acc[r];
        SIM[((size_t)(row0 + lr)) * S_ + j] = acc[r];
    }
    __syncthreads();
    int rr = tid >> 5, l32 = tid & 31;
    float v4[4];
    float m4 = -INFINITY;
#pragma unroll
    for (int i = 0; i < 4; ++i) { v4[i] = sm[rr][l32 * 4 + i]; m4 = fmaxf(m4, v4[i]); }
    redm[rr][l32] = m4;
    __syncthreads();
    for (int s = 16; s > 0; s >>= 1) {
        if (l32 < s) redm[rr][l32] = fmaxf(redm[rr][l32], redm[rr][l32 + s]);
        __syncthreads();
    }
    float mx = redm[rr][0];
    __syncthreads();
    float s4 = 0.f;
#pragma unroll
    for (int i = 0; i < 4; ++i) { v4[i] = expf(v4[i] - mx); s4 += v4[i]; }
    redm[rr][l32] = s4;
    __syncthreads();
    for (int s = 16; s > 0; s >>= 1) {
        if (l32 < s) redm[rr][l32] += redm[rr][l32 + s];
        __syncthreads();
    }
    float inv = 1.f / redm[rr][0];
    short o[4];
#pragma unroll
    for (int i = 0; i < 4; ++i) o[i] = f2s(v4[i] * inv);
    *(short4*)((short*)Wb + (size_t)(row0 + rr) * 128 + l32 * 4) = *(short4*)&o[0];
}

// ---------------------------------------------------------------------------
// Alpha softmax: Wb row 4096+blk = softmax_i SIM[b][i][r].
// ---------------------------------------------------------------------------
__global__ __launch_bounds__(128) void k_softa(const float* __restrict__ SIM,
                                               bf16* __restrict__ Wb) {
    int blk = blockIdx.x;
    int b = blk >> 7, r = blk & 127;
    int t = threadIdx.x;
    __shared__ float red[128];
    float x = SIM[((size_t)(b * S_ + t)) * S_ + r];
    red[t] = x;
    __syncthreads();
    for (int s = 64; s > 0; s >>= 1) {
        if (t < s) red[t] = fmaxf(red[t], red[t + s]);
        __syncthreads();
    }
    float mx = red[0];
    __syncthreads();
    float ex = expf(x - mx);
    red[t] = ex;
    __syncthreads();
    for (int s = 64; s > 0; s >>= 1) {
        if (t < s) red[t] += red[t + s];
        __syncthreads();
    }
    Wb[(size_t)(NT1 + blk) * 128 + t] = __float2bfloat16(ex / red[0]);
}

// ---------------------------------------------------------------------------
// Attention MFMA GEMM (validated round 13): ATT = Wb @ E-half; EA = ATT*E.
// ---------------------------------------------------------------------------
__global__ __launch_bounds__(256) void k_attg(const bf16* __restrict__ Wb,
                                              const bf16* __restrict__ E,
                                              bf16* __restrict__ ATT,
                                              bf16* __restrict__ EA) {
    __shared__ short As[64][72];
    __shared__ short Bs[64][72];
    int tid = threadIdx.x;
    int w = tid >> 6, lane = tid & 63, quad = lane >> 4, l16 = lane & 15;
    int m0 = blockIdx.x * 64;
    int kind = (m0 >= NT1) ? 1 : 0;
    int local = m0 - kind * NT1;
    int b = local >> 7;
    int ebase = kind ? (b * 128) : (NT1 + b * 128);   // opposite sentence rows
    int bn = blockIdx.y * 64;
    int wr = (w & 1) * 32, wc = (w >> 1) * 32;
    int ar = tid >> 2, ac = (tid & 3) * 16;

    f32x4 acc[2][2];
#pragma unroll
    for (int i = 0; i < 2; ++i)
#pragma unroll
        for (int j = 0; j < 2; ++j)
#pragma unroll
            for (int r = 0; r < 4; ++r) acc[i][j][r] = 0.f;

    for (int k0 = 0; k0 < 128; k0 += 64) {
        {
            const short* src = (const short*)Wb + (size_t)(m0 + ar) * 128 + k0 + ac;
#pragma unroll
            for (int i = 0; i < 4; ++i) *(short4*)&As[ar][ac + i * 4] = ((const short4*)src)[i];
        }
#pragma unroll
        for (int it = 0; it < 2; ++it) {
            int idx = tid + it * 256;
            int r = idx >> 3;
            int c8 = (idx & 7) * 8;
            const short* src = (const short*)E + (size_t)(ebase + k0 + r) * LDE + bn + c8;
            short4 v0 = ((const short4*)src)[0];
            short4 v1 = ((const short4*)src)[1];
            const short* vp = (const short*)&v0;
#pragma unroll
            for (int i = 0; i < 4; ++i) Bs[c8 + i][r] = vp[i];
            vp = (const short*)&v1;
#pragma unroll
            for (int i = 0; i < 4; ++i) Bs[c8 + 4 + i][r] = vp[i];
        }
        __syncthreads();
        {
            bf16x8 a[2][2], bb[2][2];
#pragma unroll
            for (int mt = 0; mt < 2; ++mt)
#pragma unroll
                for (int ks = 0; ks < 2; ++ks)
                    a[mt][ks] = *(const bf16x8*)&As[wr + mt * 16 + l16][ks * 32 + quad * 8];
#pragma unroll
            for (int nt = 0; nt < 2; ++nt)
#pragma unroll
                for (int ks = 0; ks < 2; ++ks)
                    bb[nt][ks] = *(const bf16x8*)&Bs[wc + nt * 16 + l16][ks * 32 + quad * 8];
#pragma unroll
            for (int mt = 0; mt < 2; ++mt)
#pragma unroll
                for (int nt = 0; nt < 2; ++nt) {
                    acc[mt][nt] = __builtin_amdgcn_mfma_f32_16x16x32_bf16(a[mt][0], bb[nt][0], acc[mt][nt], 0, 0, 0);
                    acc[mt][nt] = __builtin_amdgcn_mfma_f32_16x16x32_bf16(a[mt][1], bb[nt][1], acc[mt][nt], 0, 0, 0);
                }
        }
        __syncthreads();
    }
    short (*Cs)[72] = As;
#pragma unroll
    for (int mt = 0; mt < 2; ++mt)
#pragma unroll
        for (int nt = 0; nt < 2; ++nt) {
            int cl = wc + nt * 16 + l16;
#pragma unroll
            for (int r = 0; r < 4; ++r)
                Cs[wr + mt * 16 + quad * 4 + r][cl] = f2s(acc[mt][nt][r]);
        }
    __syncthreads();
#pragma unroll
    for (int it = 0; it < 2; ++it) {
        int chunk = tid + it * 256;
        int rl = chunk >> 3;
        int c8 = (chunk & 7) * 8;
        int row = m0 + rl;
        short a8[8];
        *(short4*)&a8[0] = *(short4*)&Cs[rl][c8];
        *(short4*)&a8[4] = *(short4*)&Cs[rl][c8 + 4];
        short* adst = (short*)ATT + (size_t)row * LDE + bn + c8;
        *(short4*)adst = *(short4*)&a8[0];
        *(short4*)(adst + 4) = *(short4*)&a8[4];
        const short* es = (const short*)E + (size_t)row * LDE + bn + c8;
        short e8[8];
        *(short4*)&e8[0] = ((const short4*)es)[0];
        *(short4*)&e8[4] = ((const short4*)es)[1];
        short o8[8];
#pragma unroll
        for (int i = 0; i < 8; ++i) o8[i] = f2s(s2f(a8[i]) * s2f(e8[i]));
        short* edst = (short*)EA + (size_t)row * LDE + bn + c8;
        *(short4*)edst = *(short4*)&o8[0];
        *(short4*)(edst + 4) = *(short4*)&o8[4];
    }
}

// ---------------------------------------------------------------------------
// Pool: V [NT, LDP] -> POOL [B,4P] fp32 (validated rounds 11-13).
// ---------------------------------------------------------------------------
__global__ __launch_bounds__(256) void k_pool(const bf16* __restrict__ V,
                                              float* __restrict__ OUT) {
    int b = blockIdx.x;
    int c = threadIdx.x;
    if (c >= P_) return;
    const bf16* v1 = V + (size_t)(b * S_) * LDP;
    const bf16* v2 = V + (size_t)(NT1 + b * S_) * LDP;
    float mx1 = -INFINITY, mx2 = -INFINITY, s1 = 0.f, s2 = 0.f;
    for (int i = 0; i < S_; ++i) {
        float a = b2f(v1[(size_t)i * LDP + c]);
        mx1 = fmaxf(mx1, a); s1 += a;
        float bb = b2f(v2[(size_t)i * LDP + c]);
        mx2 = fmaxf(mx2, bb); s2 += bb;
    }
    float* o = OUT + (size_t)b * 4 * P_;
    o[c] = mx1; o[P_ + c] = mx2; o[2 * P_ + c] = s1; o[3 * P_ + c] = s2;
}

// Sentinel fill (diagnostic: absmax ~555 => ws_size too small)
__global__ void k_fillf(float* dst, int n, float v) {
    int i = blockIdx.x * 256 + threadIdx.x;
    if (i < n) dst[i] = v;
}

// ---------------------------------------------------------------------------
// Launch
// ---------------------------------------------------------------------------
extern "C" void kernel_launch(void* const* d_in, const int* in_sizes, int n_in,
                              void* d_out, int out_size, void* d_ws, size_t ws_size,
                              hipStream_t stream) {
    const int* x1 = (const int*)d_in[0];
    const int* x2 = (const int*)d_in[1];
    const float* emb = (const float*)d_in[2];
    const float *hw1_Wh = (const float*)d_in[3],  *hw1_bh = (const float*)d_in[4];
    const float *hw1_Wt = (const float*)d_in[5],  *hw1_bt = (const float*)d_in[6];
    const float *hw2_Wh = (const float*)d_in[7],  *hw2_bh = (const float*)d_in[8];
    const float *hw2_Wt = (const float*)d_in[9],  *hw2_bt = (const float*)d_in[10];
    const float *mul_W1 = (const float*)d_in[11], *mul_b1 = (const float*)d_in[12];
    const float *mul_W2 = (const float*)d_in[13], *mul_b2 = (const float*)d_in[14];
    const float *dist_W1 = (const float*)d_in[15], *dist_b1 = (const float*)d_in[16];
    const float *dist_W2 = (const float*)d_in[17], *dist_b2 = (const float*)d_in[18];
    const float *cmp_W1 = (const float*)d_in[19], *cmp_b1 = (const float*)d_in[20];
    const float *cmp_W2 = (const float*)d_in[21], *cmp_b2 = (const float*)d_in[22];
    const float *chw1_Wh = (const float*)d_in[23], *chw1_bh = (const float*)d_in[24];
    const float *chw1_Wt = (const float*)d_in[25], *chw1_bt = (const float*)d_in[26];
    const float *chw2_Wh = (const float*)d_in[27], *chw2_bh = (const float*)d_in[28];
    const float *chw2_Wt = (const float*)d_in[29], *chw2_bt = (const float*)d_in[30];
    const float *agg_W1 = (const float*)d_in[31], *agg_b1 = (const float*)d_in[32];
    const float *agg_W2 = (const float*)d_in[33], *agg_b2 = (const float*)d_in[34];
    const float *out_W = (const float*)d_in[35], *out_b = (const float*)d_in[36];

    // ---- Workspace layout (bf16 elems), all strides 64B-aligned ----
    const size_t nE = (size_t)NT * LDE;        // 2,621,440
    const size_t nP = (size_t)NT * LDP;        // 2,097,152
    const size_t nCht = (size_t)NT * 448;      // 3,670,016
    const size_t nTR = (size_t)B_ * P_ * S_;   //   819,200
    const size_t nWT = 1224704;                // converted bf16 weights
    size_t bf16_elems = 4 * nE + 2 * nP + 2 * nCht + nWT;
    size_t f32_elems = (size_t)B_ * 4 * P_ + 2 * (size_t)B_ * P_ + 200600;
    size_t need = bf16_elems * 2 + f32_elems * 4 + 64;
    if (ws_size < need) {
        k_fillf<<<dim3(1), dim3(256), 0, stream>>>((float*)d_out, B_ * 3, 555.f);
        return;
    }
    bf16* Eb  = (bf16*)d_ws;            // [NT,LDE] embed; later ATT (dead after hw1)
    bf16* X1  = Eb + nE;                // [NT,LDE]
    bf16* X2  = X1 + nE;                // [NT,LDE] final E
    bf16* EA  = X2 + nE;                // [NT,LDE] E*ATT
    bf16* Pb  = EA + nE;                // [NT,LDP]
    bf16* Qb  = Pb + nP;                // [NT,LDP]
    bf16* ChtA = Qb + nP;               // [NT,448]
    bf16* ChtB = ChtA + nCht;           // [NT,448] PT/QT/SIM overlay / V2
    bf16* WTp = ChtB + nCht;
    float* POOL = (float*)(WTp + nWT);
    float* G1 = POOL + (size_t)B_ * 4 * P_;
    float* G2 = G1 + (size_t)B_ * P_;
    float* WT_a1 = G2 + (size_t)B_ * P_;  // [200][800]
    float* WT_a2 = WT_a1 + 160000;        // [200][200]
    float* WT_o  = WT_a2 + 40000;         // [3][200]
    bf16* ATT = Eb;                       // overlay: Eb dead after hw1
    bf16* Wbuf = ChtA;                    // [8192][128] softmax weights overlay
    // overlays inside ChtB:
    bf16* PTb = ChtB;
    bf16* QTb = ChtB + nTR;
    float* SIM = (float*)(ChtB + 2 * nTR);
    bf16* V2 = ChtB;                      // reuse after attention

    // converted-weight sub-buffers, Kpad mult of 64
    bf16* WT_hw1 = WTp + 0;        // 640x320 interleaved h|t
    bf16* WT_hw2 = WTp + 204800;   // 640x320 interleaved
    bf16* WT_md  = WTp + 409600;   // 448x320 (mul_W1 | dist_W1)
    bf16* WT_m2  = WTp + 552960;   // 256x256
    bf16* WT_d2  = WTp + 618496;   // 256x256
    bf16* WT_c2  = WTp + 684032;   // 256x256
    bf16* WT_ch1 = WTp + 749568;   // 448x256 interleaved
    bf16* WT_ch2 = WTp + 864256;   // 448x256 interleaved
    bf16* WT_c1  = WTp + 978944;   // 256x960 (combined cmp_W1)

    dim3 blk256(256);

    // 0. mega setup: weight conversions + cmp_W1 combine + embed + tail transposes
    ConvTable T;
    const float* s1[8] = {hw1_Wh, hw2_Wh, mul_W1, mul_W2, dist_W2, cmp_W2, chw1_Wh, chw2_Wh};
    const float* s2[8] = {hw1_Wt, hw2_Wt, dist_W1, nullptr, nullptr, nullptr, chw1_Wt, chw2_Wt};
    bf16* dsts[8] = {WT_hw1, WT_hw2, WT_md, WT_m2, WT_d2, WT_c2, WT_ch1, WT_ch2};
    int Ks[8]  = {300, 300, 300, 200, 200, 200, 200, 200};
    int N1s[8] = {300, 300, 200, 200, 200, 200, 200, 200};
    int N2s[8] = {300, 300, 200, 0, 0, 0, 200, 200};
    int Kps[8] = {320, 320, 320, 256, 256, 256, 256, 256};
    int Nps[8] = {640, 640, 448, 256, 256, 256, 448, 448};
    int ILs[8] = {1, 1, 0, 0, 0, 0, 1, 1};
    unsigned long long base = 0;
    for (int i = 0; i < 8; ++i) {
        T.W1[i] = s1[i]; T.W2[i] = s2[i]; T.dst[i] = dsts[i];
        T.K[i] = Ks[i]; T.N1[i] = N1s[i]; T.N2[i] = N2s[i]; T.Kpad[i] = Kps[i];
        T.IL[i] = ILs[i];
        T.base[i] = base;
        base += (unsigned long long)Kps[i] * Nps[i];
    }
    T.total = base;   // 978,944
    unsigned long long setup_total = base + 245760ull
                                   + (unsigned long long)NT * (LDE / 4) + 200600ull;
    k_setup<<<dim3((unsigned)((setup_total + 255) / 256)), blk256, 0, stream>>>(
        T, cmp_W1, WT_c1, x1, x2, emb, Eb, agg_W1, agg_W2, out_W, WT_a1, WT_a2, WT_o);

    // 1. hw1: A=Eb, interleaved h|t, fused highway (x=Eb) -> X1
    k_gemm<0, 1><<<dim3(128, 10), blk256, 0, stream>>>(
        Eb, nullptr, nullptr, LDE,
        WT_hw1, nullptr, 320, 300, X1, nullptr, LDE, 600, 300,
        hw1_bh, hw1_bt, 1, 2, Eb, LDE);

    // 2. hw2: A=X1, fused highway (x=X1) -> X2
    k_gemm<0, 1><<<dim3(128, 10), blk256, 0, stream>>>(
        X1, nullptr, nullptr, LDE,
        WT_hw2, nullptr, 320, 300, X2, nullptr, LDE, 600, 300,
        hw2_bh, hw2_bt, 1, 2, X1, LDE);

    // 3. md: A=X2 -> ChtA [NT,448] (mul hidden | dist hidden)
    k_gemm<0, 0><<<dim3(128, 7), blk256, 0, stream>>>(
        X2, nullptr, nullptr, LDE,
        WT_md, nullptr, 320, 300, ChtA, nullptr, 448, 400, 200,
        mul_b1, dist_b1, 1, 1, nullptr, 0);

    // 4. m2 + d2 dual: ChtA halves -> Pb, Qb
    k_gemm<4, 0><<<dim3(128, 8), blk256, 0, stream>>>(
        ChtA, nullptr, nullptr, 448,
        WT_m2, WT_d2, 256, 200, Pb, Qb, LDP, 256, 200,
        mul_b2, dist_b2, 1, 1, nullptr, 0);

    // 5. transpose x2-halves into ChtB overlay
    int nTRb = (int)((nTR + 255) / 256);
    k_transpose2<<<dim3(nTRb, 2), blk256, 0, stream>>>(
        Pb + (size_t)NT1 * LDP, PTb, Qb + (size_t)NT1 * LDP, QTb);

    // 6. sim + fused beta softmax -> SIM + Wbuf[0:4096]
    k_sim2<<<dim3(B_ * 16), blk256, 0, stream>>>(Pb, Qb, PTb, QTb, SIM, Wbuf);

    // 7. alpha softmax -> Wbuf[4096:8192]
    k_softa<<<dim3(NT1), dim3(128), 0, stream>>>(SIM, Wbuf);

    // 8. attention MFMA: ATT = Wbuf @ E-half, EA = ATT*E fused; E = X2
    k_attg<<<dim3(128, 5), blk256, 0, stream>>>(Wbuf, X2, ATT, EA);

    // 9. cmp1: virtual K-concat {X2, ATT, EA} -> ChtA hidden [NT,LDP]
    k_gemm<3, 0><<<dim3(128, 4), blk256, 0, stream>>>(
        X2, ATT, EA, LDE,
        WT_c1, nullptr, 960, 300, ChtA, nullptr, LDP, 200, 200,
        cmp_b1, cmp_b1, 1, 1, nullptr, 0);

    // 10. cmp2: ChtA -> Pb (Vv0)
    k_gemm<0, 0><<<dim3(128, 4), blk256, 0, stream>>>(
        ChtA, nullptr, nullptr, LDP,
        WT_c2, nullptr, 256, 200, Pb, nullptr, LDP, 200, 200,
        cmp_b2, cmp_b2, 1, 1, nullptr, 0);

    // 11. ch1: A=Pb, interleaved h|t, fused highway (x=Pb) -> Qb (V1)
    k_gemm<0, 1><<<dim3(128, 7), blk256, 0, stream>>>(
        Pb, nullptr, nullptr, LDP,
        WT_ch1, nullptr, 256, 200, Qb, nullptr, LDP, 400, 200,
        chw1_bh, chw1_bt, 1, 2, Pb, LDP);

    // 12. ch2: A=Qb, fused highway (x=Qb) -> V2 (ChtB reuse)
    k_gemm<0, 1><<<dim3(128, 7), blk256, 0, stream>>>(
        Qb, nullptr, nullptr, LDP,
        WT_ch2, nullptr, 256, 200, V2, nullptr, LDP, 400, 200,
        chw2_bh, chw2_bt, 1, 2, Qb, LDP);

    // 13. pool
    k_pool<<<dim3(B_), blk256, 0, stream>>>(V2, POOL);

    // 14-16. aggregate ff + final linear: wave-per-output skinny GEMMs
    k_skinny<<<dim3(1600), blk256, 0, stream>>>(POOL, WT_a1, agg_b1, G1, B_, P_, 800, 1);
    k_skinny<<<dim3(1600), blk256, 0, stream>>>(G1, WT_a2, agg_b2, G2, B_, P_, 200, 1);
    k_skinny<<<dim3(24), blk256, 0, stream>>>(G2, WT_o, out_b, (float*)d_out, B_, 3, 200, 0);
}